// Round 3
// baseline (524.862 us; speedup 1.0000x reference)
//
#include <hip/hip_runtime.h>

// B=16384, F=40, D=32, fp32 — fused single kernel, intermediates in LDS.
// Block = 256 thr = 4 waves, NB=4 batch elements; wave w owns fields
// [10w,10w+10). 20 KB LDS -> 8 blocks/CU -> 32 waves/CU (100% occ).
//   phase 0: stage h[b][f][d]           (coalesced bulk copy)
//   stage A: h_out = Wout[f] @ h        IN-PLACE per row (wave-private rows:
//            only the owning wave reads h[bl,f,:], so read->compute->write
//            needs no barrier and no acc buffer)
//   stage B: aggr = g @ h_out           regs; barrier; write in-place
//   stage C: out  = Win[f] @ aggr + bias -> global (wave-local rows, so only
//            s_waitcnt lgkmcnt(0) between B-write and C-read, no barrier)
// R2 lesson: 40 KB LDS capped occupancy at 16 waves/CU and 5 barriers over
// 4 blocks/CU left waves idle 92% of cycles (VALUBusy 26 @ occ 41.5).
// 3 barriers, 8 independent blocks/CU, VGPR target <=64.

#define B_TOT 16384
#define FF    40
#define DD    32
#define NB    4
#define WF    10

__global__ __launch_bounds__(256, 8)   // 8 waves/SIMD -> VGPR cap 64
void graph_layer_fused(const float* __restrict__ g,
                       const float* __restrict__ h,
                       const float* __restrict__ Win,
                       const float* __restrict__ Wout,
                       const float* __restrict__ bias,
                       float* __restrict__ out)
{
    __shared__ __attribute__((aligned(16))) float s_buf[NB * FF * DD]; // 20 KB

    const int t     = threadIdx.x;
    const int w     = t >> 6;
    const int l     = t & 63;
    const int b0    = blockIdx.x * NB;
    const int fbase = w * WF;

    // ---- phase 0: bulk-stage h for 4 b's, linear [b][f][d] ----------------
    {
        const float4* src = (const float4*)(h + (size_t)b0 * (FF * DD));
        float4* dst = (float4*)s_buf;
        #pragma unroll
        for (int k = 0; k < 5; ++k)
            dst[t + k * 256] = src[t + k * 256];
    }
    __syncthreads();

    // ---- stage A: h_out = Wout[f] @ h[b,f,:], in place --------------------
    const int d    = l & 31;
    const int half = l >> 5;
    #pragma unroll 1
    for (int fi = 0; fi < WF; ++fi) {
        const int f = fbase + fi;
        const float4* wrow = (const float4*)(Wout + ((size_t)f * DD + d) * DD);
        float4 wr[8];
        #pragma unroll
        for (int j = 0; j < 8; ++j) wr[j] = wrow[j];
        #pragma unroll
        for (int bp = 0; bp < 2; ++bp) {
            const int bl = 2 * bp + half;
            float* row = s_buf + (bl * FF + f) * DD;
            float p0 = 0.f, p1 = 0.f, p2 = 0.f, p3 = 0.f;
            #pragma unroll
            for (int j = 0; j < 8; ++j) {                 // 2-addr broadcast
                float4 hv = ((const float4*)row)[j];
                p0 += wr[j].x * hv.x; p1 += wr[j].y * hv.y;
                p2 += wr[j].z * hv.z; p3 += wr[j].w * hv.w;
            }
            // row is read only by this wave; dataflow orders reads->write
            row[d] = (p0 + p1) + (p2 + p3);
        }
    }
    __syncthreads();                       // h_out complete for all waves

    // ---- stage B: aggr = sum_G g[b,f,G] * h_out[b,G,:] --------------------
    // lane: bl = l>>4 (0..3), dq = (l>>1)&7, fh = l&1 (field half)
    const int bl = l >> 4;
    const int dq = (l >> 1) & 7;
    const int fh = l & 1;
    const int f0 = fbase + fh * 5;
    const float* grow = g + (size_t)(b0 + bl) * (FF * FF) + (size_t)f0 * FF;
    const float* sbB  = s_buf + bl * (FF * DD) + dq * 4;

    float4 accB[5];
    float4 gv[5];
    #pragma unroll
    for (int fi = 0; fi < 5; ++fi) {
        accB[fi] = make_float4(0.f, 0.f, 0.f, 0.f);
        gv[fi]   = *(const float4*)(grow + fi * FF);      // prefetch gc=0
    }
    #pragma unroll 1
    for (int gc = 0; gc < 10; ++gc) {
        const int gnx = (gc < 9) ? 4 * gc + 4 : 36;       // rolling prefetch
        // hv in pairs to keep peak VGPR low (4-way bank conflict, accepted)
        float4 h0 = *(const float4*)(sbB + (4 * gc + 0) * DD);
        float4 h1 = *(const float4*)(sbB + (4 * gc + 1) * DD);
        #pragma unroll
        for (int fi = 0; fi < 5; ++fi) {
            float4 gf = gv[fi];
            accB[fi].x += gf.x * h0.x + gf.y * h1.x;
            accB[fi].y += gf.x * h0.y + gf.y * h1.y;
            accB[fi].z += gf.x * h0.z + gf.y * h1.z;
            accB[fi].w += gf.x * h0.w + gf.y * h1.w;
        }
        float4 h2 = *(const float4*)(sbB + (4 * gc + 2) * DD);
        float4 h3 = *(const float4*)(sbB + (4 * gc + 3) * DD);
        #pragma unroll
        for (int fi = 0; fi < 5; ++fi) {
            float4 gf = gv[fi];
            accB[fi].x += gf.z * h2.x + gf.w * h3.x;
            accB[fi].y += gf.z * h2.y + gf.w * h3.y;
            accB[fi].z += gf.z * h2.z + gf.w * h3.z;
            accB[fi].w += gf.z * h2.w + gf.w * h3.w;
            gv[fi] = *(const float4*)(grow + fi * FF + gnx); // refresh after use
        }
    }
    __syncthreads();                       // all h_out reads done everywhere

    #pragma unroll
    for (int fi = 0; fi < 5; ++fi)         // aggr in place, [b][f][d]
        *(float4*)(s_buf + ((size_t)bl * FF + f0 + fi) * DD + dq * 4) = accB[fi];
    // aggr rows (bl, f in wave range) are written & read by THIS wave only:
    // drain own DS queue instead of a block barrier
    asm volatile("s_waitcnt lgkmcnt(0)" ::: "memory");

    // ---- stage C: out = Win[f] @ aggr + bias ------------------------------
    {
        const float bv = bias[d];
        #pragma unroll 1
        for (int fi = 0; fi < WF; ++fi) {
            const int f = fbase + fi;
            const float4* wrow = (const float4*)(Win + ((size_t)f * DD + d) * DD);
            float4 wr[8];
            #pragma unroll
            for (int j = 0; j < 8; ++j) wr[j] = wrow[j];
            #pragma unroll
            for (int bp = 0; bp < 2; ++bp) {
                const int bl2 = 2 * bp + half;
                const float4* arow = (const float4*)(s_buf + (bl2 * FF + f) * DD);
                float p0 = 0.f, p1 = 0.f, p2 = 0.f, p3 = 0.f;
                #pragma unroll
                for (int j = 0; j < 8; ++j) {
                    float4 av = arow[j];
                    p0 += wr[j].x * av.x; p1 += wr[j].y * av.y;
                    p2 += wr[j].z * av.z; p3 += wr[j].w * av.w;
                }
                out[((size_t)(b0 + bl2) * FF + f) * DD + d] =
                    ((p0 + p1) + (p2 + p3)) + bv;   // 128 B per half-wave
            }
        }
    }
}

extern "C" void kernel_launch(void* const* d_in, const int* in_sizes, int n_in,
                              void* d_out, int out_size, void* d_ws, size_t ws_size,
                              hipStream_t stream) {
    const float* g    = (const float*)d_in[0];
    const float* h    = (const float*)d_in[1];
    const float* Win  = (const float*)d_in[2];
    const float* Wout = (const float*)d_in[3];
    const float* bias = (const float*)d_in[4];
    float* out = (float*)d_out;

    dim3 block(256);
    dim3 grid(B_TOT / NB);   // 4096 blocks
    graph_layer_fused<<<grid, block, 0, stream>>>(g, h, Win, Wout, bias, out);
}

// Round 4
// 490.826 us; speedup vs baseline: 1.0693x; 1.0693x over previous
//
#include <hip/hip_runtime.h>

// B=16384, F=40, D=32, fp32 — fused single kernel, intermediates in LDS.
// Block = 256 thr = 4 waves, NB=4 batch elements; wave w owns fields
// [10w,10w+10). 20 KB LDS -> 8 blocks/CU possible.
//   phase 0: stage h[b][f][d]           (coalesced bulk copy)
//   stage A: h_out = Wout[f] @ h        IN-PLACE per row (wave-private rows;
//            same-wave DS ordering makes read->write safe, no barrier)
//   stage B: aggr = g @ h_out           regs; barrier; write in-place
//   stage C: out  = Win[f] @ aggr + bias -> global (wave-local rows: only
//            s_waitcnt lgkmcnt(0) between B-write and C-read, no barrier)
// R3 lesson: __launch_bounds__(256,8) forced VGPR=32 < ~60 live floats ->
// scratch spills (WRITE_SIZE 86->128 MB), VALUBusy 15.7% despite occ 81%.
// NEVER cap below live-state demand. (256,4) compiled to 64 VGPR in R2.
// Stage-B LDS pattern is at its structural bank floor (4 cyc/b128 via
// 2-way broadcast) — SQ_LDS_BANK_CONFLICT 655K is 2.5% noise, no swizzle.

#define B_TOT 16384
#define FF    40
#define DD    32
#define NB    4
#define WF    10

__global__ __launch_bounds__(256, 4)   // allow up to 128 VGPR; demand ~60
void graph_layer_fused(const float* __restrict__ g,
                       const float* __restrict__ h,
                       const float* __restrict__ Win,
                       const float* __restrict__ Wout,
                       const float* __restrict__ bias,
                       float* __restrict__ out)
{
    __shared__ __attribute__((aligned(16))) float s_buf[NB * FF * DD]; // 20 KB

    const int t     = threadIdx.x;
    const int w     = t >> 6;
    const int l     = t & 63;
    const int b0    = blockIdx.x * NB;
    const int fbase = w * WF;

    // ---- phase 0: bulk-stage h for 4 b's, linear [b][f][d] ----------------
    {
        const float4* src = (const float4*)(h + (size_t)b0 * (FF * DD));
        float4* dst = (float4*)s_buf;
        #pragma unroll
        for (int k = 0; k < 5; ++k)
            dst[t + k * 256] = src[t + k * 256];
    }
    __syncthreads();

    // ---- stage A: h_out = Wout[f] @ h[b,f,:], in place --------------------
    const int d    = l & 31;
    const int half = l >> 5;
    #pragma unroll 1
    for (int fi = 0; fi < WF; ++fi) {
        const int f = fbase + fi;
        const float4* wrow = (const float4*)(Wout + ((size_t)f * DD + d) * DD);
        float4 wr[8];
        #pragma unroll
        for (int j = 0; j < 8; ++j) wr[j] = wrow[j];
        #pragma unroll
        for (int bp = 0; bp < 2; ++bp) {
            const int bl = 2 * bp + half;
            float* row = s_buf + (bl * FF + f) * DD;
            float p0 = 0.f, p1 = 0.f, p2 = 0.f, p3 = 0.f;
            #pragma unroll
            for (int j = 0; j < 8; ++j) {                 // 2-addr broadcast
                float4 hv = ((const float4*)row)[j];
                p0 += wr[j].x * hv.x; p1 += wr[j].y * hv.y;
                p2 += wr[j].z * hv.z; p3 += wr[j].w * hv.w;
            }
            // row is read only by this wave; same-wave DS order: reads<write
            row[d] = (p0 + p1) + (p2 + p3);
        }
    }
    __syncthreads();                       // h_out complete for all waves

    // ---- stage B: aggr = sum_G g[b,f,G] * h_out[b,G,:] --------------------
    // lane: bl = l>>4 (0..3), dq = (l>>1)&7, fh = l&1 (field half)
    const int bl = l >> 4;
    const int dq = (l >> 1) & 7;
    const int fh = l & 1;
    const int f0 = fbase + fh * 5;
    const float* grow = g + (size_t)(b0 + bl) * (FF * FF) + (size_t)f0 * FF;
    const float* sbB  = s_buf + bl * (FF * DD) + dq * 4;

    float4 accB[5];
    float4 gv[5];
    #pragma unroll
    for (int fi = 0; fi < 5; ++fi) {
        accB[fi] = make_float4(0.f, 0.f, 0.f, 0.f);
        gv[fi]   = *(const float4*)(grow + fi * FF);      // prefetch gc=0
    }
    #pragma unroll 1
    for (int gc = 0; gc < 10; ++gc) {
        const int gnx = (gc < 9) ? 4 * gc + 4 : 36;       // rolling prefetch
        float4 h0 = *(const float4*)(sbB + (4 * gc + 0) * DD);
        float4 h1 = *(const float4*)(sbB + (4 * gc + 1) * DD);
        #pragma unroll
        for (int fi = 0; fi < 5; ++fi) {
            float4 gf = gv[fi];
            accB[fi].x += gf.x * h0.x + gf.y * h1.x;
            accB[fi].y += gf.x * h0.y + gf.y * h1.y;
            accB[fi].z += gf.x * h0.z + gf.y * h1.z;
            accB[fi].w += gf.x * h0.w + gf.y * h1.w;
        }
        float4 h2 = *(const float4*)(sbB + (4 * gc + 2) * DD);
        float4 h3 = *(const float4*)(sbB + (4 * gc + 3) * DD);
        #pragma unroll
        for (int fi = 0; fi < 5; ++fi) {
            float4 gf = gv[fi];
            accB[fi].x += gf.z * h2.x + gf.w * h3.x;
            accB[fi].y += gf.z * h2.y + gf.w * h3.y;
            accB[fi].z += gf.z * h2.z + gf.w * h3.z;
            accB[fi].w += gf.z * h2.w + gf.w * h3.w;
            gv[fi] = *(const float4*)(grow + fi * FF + gnx); // refresh after use
        }
    }
    __syncthreads();                       // all h_out reads done everywhere

    #pragma unroll
    for (int fi = 0; fi < 5; ++fi)         // aggr in place, [b][f][d]
        *(float4*)(s_buf + ((size_t)bl * FF + f0 + fi) * DD + dq * 4) = accB[fi];
    // aggr rows (bl, f in wave range) are written & read by THIS wave only:
    // drain own DS queue instead of a block barrier
    asm volatile("s_waitcnt lgkmcnt(0)" ::: "memory");

    // ---- stage C: out = Win[f] @ aggr + bias ------------------------------
    {
        const float bv = bias[d];
        #pragma unroll 1
        for (int fi = 0; fi < WF; ++fi) {
            const int f = fbase + fi;
            const float4* wrow = (const float4*)(Win + ((size_t)f * DD + d) * DD);
            float4 wr[8];
            #pragma unroll
            for (int j = 0; j < 8; ++j) wr[j] = wrow[j];
            #pragma unroll
            for (int bp = 0; bp < 2; ++bp) {
                const int bl2 = 2 * bp + half;
                const float4* arow = (const float4*)(s_buf + (bl2 * FF + f) * DD);
                float p0 = 0.f, p1 = 0.f, p2 = 0.f, p3 = 0.f;
                #pragma unroll
                for (int j = 0; j < 8; ++j) {
                    float4 av = arow[j];
                    p0 += wr[j].x * av.x; p1 += wr[j].y * av.y;
                    p2 += wr[j].z * av.z; p3 += wr[j].w * av.w;
                }
                out[((size_t)(b0 + bl2) * FF + f) * DD + d] =
                    ((p0 + p1) + (p2 + p3)) + bv;   // 128 B per half-wave
            }
        }
    }
}

extern "C" void kernel_launch(void* const* d_in, const int* in_sizes, int n_in,
                              void* d_out, int out_size, void* d_ws, size_t ws_size,
                              hipStream_t stream) {
    const float* g    = (const float*)d_in[0];
    const float* h    = (const float*)d_in[1];
    const float* Win  = (const float*)d_in[2];
    const float* Wout = (const float*)d_in[3];
    const float* bias = (const float*)d_in[4];
    float* out = (float*)d_out;

    dim3 block(256);
    dim3 grid(B_TOT / NB);   // 4096 blocks
    graph_layer_fused<<<grid, block, 0, stream>>>(g, h, Win, Wout, bias, out);
}